// Round 7
// baseline (149.352 us; speedup 1.0000x reference)
//
#include <hip/hip_runtime.h>
#include <math.h>

// Problem constants
#define PB 8
#define PT 12
#define PN 307
#define NP 320                      // padded N for MFMA tiling
#define SCALE 0.35355339059327373f  // 1/sqrt(8)

typedef short bf16x8 __attribute__((ext_vector_type(8)));
typedef float f32x4  __attribute__((ext_vector_type(4)));
// 4-byte-aligned vectors for rows whose base is only 4B-aligned (307-stride)
typedef int   i32x4u __attribute__((ext_vector_type(4), aligned(4)));
typedef float f32x4u __attribute__((ext_vector_type(4), aligned(4)));

__device__ __forceinline__ unsigned short f32_to_bf16(float v) {
    unsigned u = __float_as_uint(v);
    u += 0x7FFFu + ((u >> 16) & 1u);   // RNE
    return (unsigned short)(u >> 16);
}

__device__ __forceinline__ bf16x8 pack8(float4 lo, float4 hi) {
    bf16x8 r;
    r[0] = (short)f32_to_bf16(lo.x); r[1] = (short)f32_to_bf16(lo.y);
    r[2] = (short)f32_to_bf16(lo.z); r[3] = (short)f32_to_bf16(lo.w);
    r[4] = (short)f32_to_bf16(hi.x); r[5] = (short)f32_to_bf16(hi.y);
    r[6] = (short)f32_to_bf16(hi.z); r[7] = (short)f32_to_bf16(hi.w);
    return r;
}

// ---------------------------------------------------------------------------
// Kernel A v5 — IDENTICAL to R6 (diagnostic round: do not touch).
// ---------------------------------------------------------------------------
__global__ __launch_bounds__(256) void qk_proj_kernel(
    const float* __restrict__ x,
    const float* __restrict__ Wq, const float* __restrict__ bq,
    const float* __restrict__ Wk, const float* __restrict__ bk,
    unsigned short* __restrict__ qws, unsigned short* __restrict__ kws)
{
    const int tid  = threadIdx.x;
    const int lane = tid & 63;
    const int wv   = tid >> 6;
    const int wn   = wv & 1;
    const int we   = wv >> 1;
    const int chunk = blockIdx.x % 10;
    const int bt    = blockIdx.x / 10;
    const int b = bt / PT, t = bt % PT;
    const int rlo = lane & 15;
    const int kq  = lane >> 4;
    const int n0  = chunk * 32 + wn * 16;        // wave's n-tile base

    // A fragments: xT[n][c], n = n0+rlo (clamped), c = ks*32+kq*8+j
    const int nn = min(n0 + rlo, PN - 1);
    const float* xrow = x + ((size_t)b * 64 * PT + t) * PN + nn;  // + c*PT*PN
    bf16x8 a[2];
    #pragma unroll
    for (int ks = 0; ks < 2; ++ks) {
        #pragma unroll
        for (int j = 0; j < 8; ++j) {
            const int c = ks * 32 + kq * 8 + j;
            a[ks][j] = (short)f32_to_bf16(xrow[(size_t)c * PT * PN]);
        }
    }

    // B fragments: W rows e = we*32 + eti*16 + rlo (waves share via L1)
    f32x4 accq[2] = {}, acck[2] = {};
    #pragma unroll
    for (int eti = 0; eti < 2; ++eti) {
        const int e_row = we * 32 + eti * 16 + rlo;
        const float* wq_r = Wq + (size_t)e_row * 64 + kq * 8;
        const float* wk_r = Wk + (size_t)e_row * 64 + kq * 8;
        #pragma unroll
        for (int ks = 0; ks < 2; ++ks) {
            const bf16x8 bqf = pack8(*(const float4*)(wq_r + ks * 32),
                                     *(const float4*)(wq_r + ks * 32 + 4));
            const bf16x8 bkf = pack8(*(const float4*)(wk_r + ks * 32),
                                     *(const float4*)(wk_r + ks * 32 + 4));
            accq[eti] = __builtin_amdgcn_mfma_f32_16x16x32_bf16(a[ks], bqf, accq[eti], 0, 0, 0);
            acck[eti] = __builtin_amdgcn_mfma_f32_16x16x32_bf16(a[ks], bkf, acck[eti], 0, 0, 0);
        }
    }

    // Epilogue: bias + bf16 + store.
    #pragma unroll
    for (int eti = 0; eti < 2; ++eti) {
        const int e = we * 32 + eti * 16 + rlo;
        const float bqv = bq[e], bkv = bk[e];
        #pragma unroll
        for (int r = 0; r < 4; ++r) {
            const int n = n0 + kq * 4 + r;
            if (n < PN) {
                qws[((size_t)bt * NP + n) * 64 + e] = f32_to_bf16(accq[eti][r] + bqv);
                kws[((size_t)bt * NP + n) * 64 + e] = f32_to_bf16(acck[eti][r] + bkv);
            }
        }
    }
}

// ---------------------------------------------------------------------------
// Kernel B v4 — IDENTICAL to R6 (diagnostic round: do not touch).
// Launched 3x from kernel_launch: idempotent, so output is unchanged;
// total_R7 - total_R6 = 2 * attn_dur. This is the measurement.
// ---------------------------------------------------------------------------
__global__ __launch_bounds__(256) void attn_kernel(
    const unsigned short* __restrict__ qws,
    const unsigned short* __restrict__ kws,
    const int* __restrict__ mask,
    float* __restrict__ out)
{
    __shared__ float redmx[4][16];
    __shared__ float redsm[4][16];

    const int tid  = threadIdx.x;
    const int lane = tid & 63;
    const int wm   = tid >> 6;               // m-quarter
    const int ntile = blockIdx.x % 20;
    const int bt    = blockIdx.x / 20;
    const int b     = bt / PT;
    const int ng  = ntile * 16;
    const int nl  = lane & 15;
    const int kq  = lane >> 4;
    const int n   = ng + nl;
    const int nn  = (n < PN) ? n : (PN - 1); // clamp for mask row reads

    const bf16x8* qp = (const bf16x8*)(qws + ((size_t)bt * NP + n) * 64 + kq * 8);
    const bf16x8 bq0 = qp[0], bq1 = qp[4];
    const unsigned short* kbase = kws + ((size_t)bt * NP + nl) * 64 + kq * 8;

    f32x4 acc[5] = {};
    #pragma unroll
    for (int i = 0; i < 5; ++i) {
        const int ct = wm * 5 + i;
        const unsigned short* kb = kbase + (size_t)ct * 16 * 64;
        const bf16x8 a0 = *(const bf16x8*)(kb);
        const bf16x8 a1 = *(const bf16x8*)(kb + 32);
        acc[i] = __builtin_amdgcn_mfma_f32_16x16x32_bf16(a0, bq0, acc[i], 0, 0, 0);
        acc[i] = __builtin_amdgcn_mfma_f32_16x16x32_bf16(a1, bq1, acc[i], 0, 0, 0);
    }

    const int* mrow = mask + ((size_t)b * PN + nn) * PN;
    float mx = -INFINITY;
    #pragma unroll
    for (int i = 0; i < 5; ++i) {
        const int ct = wm * 5 + i;
        const int m0 = ct * 16 + kq * 4;
        const i32x4u mv = *(const i32x4u*)(mrow + m0);
        float sv[4];
        sv[0] = mv[0] ? acc[i][0] * SCALE : -1e9f;
        sv[1] = mv[1] ? acc[i][1] * SCALE : -1e9f;
        sv[2] = mv[2] ? acc[i][2] * SCALE : -1e9f;
        sv[3] = mv[3] ? acc[i][3] * SCALE : -1e9f;
        if (ct == 19) {
            #pragma unroll
            for (int r = 0; r < 4; ++r)
                if (m0 + r >= PN) sv[r] = -INFINITY;
        }
        #pragma unroll
        for (int r = 0; r < 4; ++r) { acc[i][r] = sv[r]; mx = fmaxf(mx, sv[r]); }
    }
    mx = fmaxf(mx, __shfl_xor(mx, 16));
    mx = fmaxf(mx, __shfl_xor(mx, 32));
    if (lane < 16) redmx[wm][lane] = mx;
    __syncthreads();
    const float gmx = fmaxf(fmaxf(redmx[0][nl], redmx[1][nl]),
                            fmaxf(redmx[2][nl], redmx[3][nl]));

    float sum = 0.f;
    #pragma unroll
    for (int i = 0; i < 5; ++i) {
        #pragma unroll
        for (int r = 0; r < 4; ++r) {
            const float p = __expf(acc[i][r] - gmx);
            acc[i][r] = p;
            sum += p;
        }
    }
    sum += __shfl_xor(sum, 16);
    sum += __shfl_xor(sum, 32);
    if (lane < 16) redsm[wm][lane] = sum;
    __syncthreads();
    const float inv = 1.0f / (redsm[0][nl] + redsm[1][nl] +
                              redsm[2][nl] + redsm[3][nl]);

    if (n < PN) {
        float* orow = out + ((size_t)bt * PN + n) * PN;
        #pragma unroll
        for (int i = 0; i < 5; ++i) {
            const int ct = wm * 5 + i;
            const int m0 = ct * 16 + kq * 4;
            if (ct < 19) {
                f32x4u o;
                o[0] = acc[i][0] * inv; o[1] = acc[i][1] * inv;
                o[2] = acc[i][2] * inv; o[3] = acc[i][3] * inv;
                *(f32x4u*)(orow + m0) = o;
            } else {
                #pragma unroll
                for (int r = 0; r < 4; ++r)
                    if (m0 + r < PN) orow[m0 + r] = acc[i][r] * inv;
            }
        }
    }
}

extern "C" void kernel_launch(void* const* d_in, const int* in_sizes, int n_in,
                              void* d_out, int out_size, void* d_ws, size_t ws_size,
                              hipStream_t stream) {
    const float* x  = (const float*)d_in[0];
    const int* mask = (const int*)d_in[1];
    const float* Wq = (const float*)d_in[2];
    const float* bq = (const float*)d_in[3];
    const float* Wk = (const float*)d_in[4];
    const float* bk = (const float*)d_in[5];
    float* out = (float*)d_out;

    // workspace: qws bf16 [96][320][64], kws bf16 [96][320][64]  (7.86 MB)
    unsigned short* qws = (unsigned short*)d_ws;
    unsigned short* kws = qws + (size_t)96 * NP * 64;

    qk_proj_kernel<<<dim3(96 * 10), dim3(256), 0, stream>>>(x, Wq, bq, Wk, bk, qws, kws);
    // DIAGNOSTIC: attn launched 3x (idempotent -> identical output).
    // total_R7 - total_R6 = 2 * attn_dur isolates attn's cost.
    attn_kernel<<<dim3(96 * 20), dim3(256), 0, stream>>>(qws, kws, mask, out);
    attn_kernel<<<dim3(96 * 20), dim3(256), 0, stream>>>(qws, kws, mask, out);
    attn_kernel<<<dim3(96 * 20), dim3(256), 0, stream>>>(qws, kws, mask, out);
}

// Round 8
// 124.829 us; speedup vs baseline: 1.1965x; 1.1965x over previous
//
#include <hip/hip_runtime.h>
#include <math.h>

// Problem constants
#define PB 8
#define PT 12
#define PN 307
#define NP 320                      // padded N for MFMA tiling
#define SCALE 0.35355339059327373f  // 1/sqrt(8)

typedef short bf16x8 __attribute__((ext_vector_type(8)));
typedef float f32x4  __attribute__((ext_vector_type(4)));
// 4-byte-aligned vectors for rows whose base is only 4B-aligned (307-stride)
typedef int   i32x4u __attribute__((ext_vector_type(4), aligned(4)));
typedef float f32x4u __attribute__((ext_vector_type(4), aligned(4)));

__device__ __forceinline__ unsigned short f32_to_bf16(float v) {
    unsigned u = __float_as_uint(v);
    u += 0x7FFFu + ((u >> 16) & 1u);   // RNE
    return (unsigned short)(u >> 16);
}

__device__ __forceinline__ bf16x8 pack8(float4 lo, float4 hi) {
    bf16x8 r;
    r[0] = (short)f32_to_bf16(lo.x); r[1] = (short)f32_to_bf16(lo.y);
    r[2] = (short)f32_to_bf16(lo.z); r[3] = (short)f32_to_bf16(lo.w);
    r[4] = (short)f32_to_bf16(hi.x); r[5] = (short)f32_to_bf16(hi.y);
    r[6] = (short)f32_to_bf16(hi.z); r[7] = (short)f32_to_bf16(hi.w);
    return r;
}

// ---------------------------------------------------------------------------
// Kernel A v6 = R6 structure + XCD swizzle.
// Grid 960: bid = (t*10 + chunk)*8 + b  ->  all blocks of batch b on XCD b%8
// (round-robin bid%8 heuristic; correctness independent of mapping).
// Block 256 = 4 waves; wave (wn,we): n-tile chunk*32+wn*16, e-range we*32.
// ---------------------------------------------------------------------------
__global__ __launch_bounds__(256) void qk_proj_kernel(
    const float* __restrict__ x,
    const float* __restrict__ Wq, const float* __restrict__ bq,
    const float* __restrict__ Wk, const float* __restrict__ bk,
    unsigned short* __restrict__ qws, unsigned short* __restrict__ kws)
{
    const int tid  = threadIdx.x;
    const int lane = tid & 63;
    const int wv   = tid >> 6;
    const int wn   = wv & 1;
    const int we   = wv >> 1;
    const int bid  = blockIdx.x;
    const int b    = bid & 7;
    const int rest = bid >> 3;
    const int t     = rest / 10;
    const int chunk = rest % 10;
    const int bt    = b * PT + t;
    const int rlo = lane & 15;
    const int kq  = lane >> 4;
    const int n0  = chunk * 32 + wn * 16;        // wave's n-tile base

    // A fragments: xT[n][c], n = n0+rlo (clamped), c = ks*32+kq*8+j
    const int nn = min(n0 + rlo, PN - 1);
    const float* xrow = x + ((size_t)b * 64 * PT + t) * PN + nn;  // + c*PT*PN
    bf16x8 a[2];
    #pragma unroll
    for (int ks = 0; ks < 2; ++ks) {
        #pragma unroll
        for (int j = 0; j < 8; ++j) {
            const int c = ks * 32 + kq * 8 + j;
            a[ks][j] = (short)f32_to_bf16(xrow[(size_t)c * PT * PN]);
        }
    }

    // B fragments: W rows e = we*32 + eti*16 + rlo (waves share via L1)
    f32x4 accq[2] = {}, acck[2] = {};
    #pragma unroll
    for (int eti = 0; eti < 2; ++eti) {
        const int e_row = we * 32 + eti * 16 + rlo;
        const float* wq_r = Wq + (size_t)e_row * 64 + kq * 8;
        const float* wk_r = Wk + (size_t)e_row * 64 + kq * 8;
        #pragma unroll
        for (int ks = 0; ks < 2; ++ks) {
            const bf16x8 bqf = pack8(*(const float4*)(wq_r + ks * 32),
                                     *(const float4*)(wq_r + ks * 32 + 4));
            const bf16x8 bkf = pack8(*(const float4*)(wk_r + ks * 32),
                                     *(const float4*)(wk_r + ks * 32 + 4));
            accq[eti] = __builtin_amdgcn_mfma_f32_16x16x32_bf16(a[ks], bqf, accq[eti], 0, 0, 0);
            acck[eti] = __builtin_amdgcn_mfma_f32_16x16x32_bf16(a[ks], bkf, acck[eti], 0, 0, 0);
        }
    }

    // Epilogue: bias + bf16 + store (stays in this XCD's L2 for attn to read).
    #pragma unroll
    for (int eti = 0; eti < 2; ++eti) {
        const int e = we * 32 + eti * 16 + rlo;
        const float bqv = bq[e], bkv = bk[e];
        #pragma unroll
        for (int r = 0; r < 4; ++r) {
            const int n = n0 + kq * 4 + r;
            if (n < PN) {
                qws[((size_t)bt * NP + n) * 64 + e] = f32_to_bf16(accq[eti][r] + bqv);
                kws[((size_t)bt * NP + n) * 64 + e] = f32_to_bf16(acck[eti][r] + bkv);
            }
        }
    }
}

// ---------------------------------------------------------------------------
// Kernel B v5 = R6 structure + XCD swizzle + non-temporal output stores.
// Grid 1920: bid = (t*20 + ntile)*8 + b -> batch b's K/Q/mask stay in one
// XCD's L2 (K/Q tiles re-read by 20 blocks, mask[b] by 240 blocks).
// Non-temporal stores keep the 36-MB out stream from evicting them.
// ---------------------------------------------------------------------------
__global__ __launch_bounds__(256) void attn_kernel(
    const unsigned short* __restrict__ qws,
    const unsigned short* __restrict__ kws,
    const int* __restrict__ mask,
    float* __restrict__ out)
{
    __shared__ float redmx[4][16];
    __shared__ float redsm[4][16];

    const int tid  = threadIdx.x;
    const int lane = tid & 63;
    const int wm   = tid >> 6;               // m-quarter
    const int bid  = blockIdx.x;
    const int b    = bid & 7;
    const int rest = bid >> 3;
    const int t     = rest / 20;
    const int ntile = rest % 20;
    const int bt    = b * PT + t;
    const int ng  = ntile * 16;
    const int nl  = lane & 15;
    const int kq  = lane >> 4;
    const int n   = ng + nl;
    const int nn  = (n < PN) ? n : (PN - 1); // clamp for mask row reads

    const bf16x8* qp = (const bf16x8*)(qws + ((size_t)bt * NP + n) * 64 + kq * 8);
    const bf16x8 bq0 = qp[0], bq1 = qp[4];
    const unsigned short* kbase = kws + ((size_t)bt * NP + nl) * 64 + kq * 8;

    f32x4 acc[5] = {};
    #pragma unroll
    for (int i = 0; i < 5; ++i) {
        const int ct = wm * 5 + i;
        const unsigned short* kb = kbase + (size_t)ct * 16 * 64;
        const bf16x8 a0 = *(const bf16x8*)(kb);
        const bf16x8 a1 = *(const bf16x8*)(kb + 32);
        acc[i] = __builtin_amdgcn_mfma_f32_16x16x32_bf16(a0, bq0, acc[i], 0, 0, 0);
        acc[i] = __builtin_amdgcn_mfma_f32_16x16x32_bf16(a1, bq1, acc[i], 0, 0, 0);
    }

    const int* mrow = mask + ((size_t)b * PN + nn) * PN;
    float mx = -INFINITY;
    #pragma unroll
    for (int i = 0; i < 5; ++i) {
        const int ct = wm * 5 + i;
        const int m0 = ct * 16 + kq * 4;
        const i32x4u mv = *(const i32x4u*)(mrow + m0);
        float sv[4];
        sv[0] = mv[0] ? acc[i][0] * SCALE : -1e9f;
        sv[1] = mv[1] ? acc[i][1] * SCALE : -1e9f;
        sv[2] = mv[2] ? acc[i][2] * SCALE : -1e9f;
        sv[3] = mv[3] ? acc[i][3] * SCALE : -1e9f;
        if (ct == 19) {                       // pad columns m >= 307 (wave-uniform)
            #pragma unroll
            for (int r = 0; r < 4; ++r)
                if (m0 + r >= PN) sv[r] = -INFINITY;
        }
        #pragma unroll
        for (int r = 0; r < 4; ++r) { acc[i][r] = sv[r]; mx = fmaxf(mx, sv[r]); }
    }
    mx = fmaxf(mx, __shfl_xor(mx, 16));
    mx = fmaxf(mx, __shfl_xor(mx, 32));
    if (lane < 16) redmx[wm][lane] = mx;
    __syncthreads();
    const float gmx = fmaxf(fmaxf(redmx[0][nl], redmx[1][nl]),
                            fmaxf(redmx[2][nl], redmx[3][nl]));

    float sum = 0.f;
    #pragma unroll
    for (int i = 0; i < 5; ++i) {
        #pragma unroll
        for (int r = 0; r < 4; ++r) {
            const float p = __expf(acc[i][r] - gmx);
            acc[i][r] = p;
            sum += p;
        }
    }
    sum += __shfl_xor(sum, 16);
    sum += __shfl_xor(sum, 32);
    if (lane < 16) redsm[wm][lane] = sum;
    __syncthreads();
    const float inv = 1.0f / (redsm[0][nl] + redsm[1][nl] +
                              redsm[2][nl] + redsm[3][nl]);

    if (n < PN) {
        float* orow = out + ((size_t)bt * PN + n) * PN;
        #pragma unroll
        for (int i = 0; i < 5; ++i) {
            const int ct = wm * 5 + i;
            const int m0 = ct * 16 + kq * 4;
            if (ct < 19) {
                f32x4u o;
                o[0] = acc[i][0] * inv; o[1] = acc[i][1] * inv;
                o[2] = acc[i][2] * inv; o[3] = acc[i][3] * inv;
                __builtin_nontemporal_store(o, (f32x4u*)(orow + m0));
            } else {
                #pragma unroll
                for (int r = 0; r < 4; ++r)
                    if (m0 + r < PN)
                        __builtin_nontemporal_store(acc[i][r] * inv, orow + m0 + r);
            }
        }
    }
}

extern "C" void kernel_launch(void* const* d_in, const int* in_sizes, int n_in,
                              void* d_out, int out_size, void* d_ws, size_t ws_size,
                              hipStream_t stream) {
    const float* x  = (const float*)d_in[0];
    const int* mask = (const int*)d_in[1];
    const float* Wq = (const float*)d_in[2];
    const float* bq = (const float*)d_in[3];
    const float* Wk = (const float*)d_in[4];
    const float* bk = (const float*)d_in[5];
    float* out = (float*)d_out;

    // workspace: qws bf16 [96][320][64], kws bf16 [96][320][64]  (7.86 MB)
    unsigned short* qws = (unsigned short*)d_ws;
    unsigned short* kws = qws + (size_t)96 * NP * 64;

    qk_proj_kernel<<<dim3(96 * 10), dim3(256), 0, stream>>>(x, Wq, bq, Wk, bk, qws, kws);
    attn_kernel<<<dim3(96 * 20), dim3(256), 0, stream>>>(qws, kws, mask, out);
}

// Round 9
// 104.166 us; speedup vs baseline: 1.4338x; 1.1984x over previous
//
#include <hip/hip_runtime.h>
#include <math.h>

// Problem constants
#define PB 8
#define PT 12
#define PN 307
#define NP 320                      // padded N for MFMA tiling
#define SCALE 0.35355339059327373f  // 1/sqrt(8)

typedef short bf16x8 __attribute__((ext_vector_type(8)));
typedef float f32x4  __attribute__((ext_vector_type(4)));
// 4-byte-aligned vectors for rows whose base is only 4B-aligned (307-stride)
typedef int   i32x4u __attribute__((ext_vector_type(4), aligned(4)));
typedef float f32x4u __attribute__((ext_vector_type(4), aligned(4)));

__device__ __forceinline__ unsigned short f32_to_bf16(float v) {
    unsigned u = __float_as_uint(v);
    u += 0x7FFFu + ((u >> 16) & 1u);   // RNE
    return (unsigned short)(u >> 16);
}

__device__ __forceinline__ bf16x8 pack8(float4 lo, float4 hi) {
    bf16x8 r;
    r[0] = (short)f32_to_bf16(lo.x); r[1] = (short)f32_to_bf16(lo.y);
    r[2] = (short)f32_to_bf16(lo.z); r[3] = (short)f32_to_bf16(lo.w);
    r[4] = (short)f32_to_bf16(hi.x); r[5] = (short)f32_to_bf16(hi.y);
    r[6] = (short)f32_to_bf16(hi.z); r[7] = (short)f32_to_bf16(hi.w);
    return r;
}

// ---------------------------------------------------------------------------
// Kernel A — EXACT R6 version (measured-good; no swizzle).
// Grid 960: bid = bt*10 + chunk. Block 256 = 4 waves; wave (wn,we):
// n-tile chunk*32+wn*16, e-range we*32.
// ---------------------------------------------------------------------------
__global__ __launch_bounds__(256) void qk_proj_kernel(
    const float* __restrict__ x,
    const float* __restrict__ Wq, const float* __restrict__ bq,
    const float* __restrict__ Wk, const float* __restrict__ bk,
    unsigned short* __restrict__ qws, unsigned short* __restrict__ kws)
{
    const int tid  = threadIdx.x;
    const int lane = tid & 63;
    const int wv   = tid >> 6;
    const int wn   = wv & 1;
    const int we   = wv >> 1;
    const int chunk = blockIdx.x % 10;
    const int bt    = blockIdx.x / 10;
    const int b = bt / PT, t = bt % PT;
    const int rlo = lane & 15;
    const int kq  = lane >> 4;
    const int n0  = chunk * 32 + wn * 16;        // wave's n-tile base

    // A fragments: xT[n][c], n = n0+rlo (clamped), c = ks*32+kq*8+j
    const int nn = min(n0 + rlo, PN - 1);
    const float* xrow = x + ((size_t)b * 64 * PT + t) * PN + nn;  // + c*PT*PN
    bf16x8 a[2];
    #pragma unroll
    for (int ks = 0; ks < 2; ++ks) {
        #pragma unroll
        for (int j = 0; j < 8; ++j) {
            const int c = ks * 32 + kq * 8 + j;
            a[ks][j] = (short)f32_to_bf16(xrow[(size_t)c * PT * PN]);
        }
    }

    // B fragments: W rows e = we*32 + eti*16 + rlo (waves share via L1)
    f32x4 accq[2] = {}, acck[2] = {};
    #pragma unroll
    for (int eti = 0; eti < 2; ++eti) {
        const int e_row = we * 32 + eti * 16 + rlo;
        const float* wq_r = Wq + (size_t)e_row * 64 + kq * 8;
        const float* wk_r = Wk + (size_t)e_row * 64 + kq * 8;
        #pragma unroll
        for (int ks = 0; ks < 2; ++ks) {
            const bf16x8 bqf = pack8(*(const float4*)(wq_r + ks * 32),
                                     *(const float4*)(wq_r + ks * 32 + 4));
            const bf16x8 bkf = pack8(*(const float4*)(wk_r + ks * 32),
                                     *(const float4*)(wk_r + ks * 32 + 4));
            accq[eti] = __builtin_amdgcn_mfma_f32_16x16x32_bf16(a[ks], bqf, accq[eti], 0, 0, 0);
            acck[eti] = __builtin_amdgcn_mfma_f32_16x16x32_bf16(a[ks], bkf, acck[eti], 0, 0, 0);
        }
    }

    // Epilogue: bias + bf16 + store.
    #pragma unroll
    for (int eti = 0; eti < 2; ++eti) {
        const int e = we * 32 + eti * 16 + rlo;
        const float bqv = bq[e], bkv = bk[e];
        #pragma unroll
        for (int r = 0; r < 4; ++r) {
            const int n = n0 + kq * 4 + r;
            if (n < PN) {
                qws[((size_t)bt * NP + n) * 64 + e] = f32_to_bf16(accq[eti][r] + bqv);
                kws[((size_t)bt * NP + n) * 64 + e] = f32_to_bf16(acck[eti][r] + bkv);
            }
        }
    }
}

// ---------------------------------------------------------------------------
// Kernel B v6 = R6 structure + inner loop over 4 t-values (mask reuse).
// Grid 480: bid = (b*3 + tg)*20 + ntile -> 20 consecutive blocks share
// (b,tg): same 4 K/Q tile-sets + same mask[b] (R6's proven temporal
// locality, no XCD assumptions). Mask row fragments loaded ONCE into 20
// VGPRs, reused across 4 t iterations (mask logical traffic 36 -> 9 MB).
// Softmax reduction buffers parity-double-buffered over tt: 2 barriers/iter,
// no store-drain barrier at loop end.
// ---------------------------------------------------------------------------
__global__ __launch_bounds__(256) void attn_kernel(
    const unsigned short* __restrict__ qws,
    const unsigned short* __restrict__ kws,
    const int* __restrict__ mask,
    float* __restrict__ out)
{
    __shared__ float redmx[2][4][16];
    __shared__ float redsm[2][4][16];

    const int tid  = threadIdx.x;
    const int lane = tid & 63;
    const int wm   = tid >> 6;               // m-quarter
    const int bid   = blockIdx.x;
    const int ntile = bid % 20;
    const int r2    = bid / 20;
    const int tg    = r2 % 3;
    const int b     = r2 / 3;
    const int ng  = ntile * 16;
    const int nl  = lane & 15;
    const int kq  = lane >> 4;
    const int n   = ng + nl;
    const int nn  = (n < PN) ? n : (PN - 1); // clamp for mask row reads

    // ---- mask fragments: loaded once, reused for all 4 t iterations
    const int* mrow = mask + ((size_t)b * PN + nn) * PN;
    i32x4u mv[5];
    #pragma unroll
    for (int i = 0; i < 5; ++i)
        mv[i] = *(const i32x4u*)(mrow + (wm * 5 + i) * 16 + kq * 4);

    #pragma unroll 1
    for (int tt = 0; tt < 4; ++tt) {
        const int t  = tg * 4 + tt;
        const int bt = b * PT + t;
        const int p  = tt & 1;               // parity buffer index

        // B fragments (Q row n; pad rows in-bounds garbage, discarded)
        const bf16x8* qp = (const bf16x8*)(qws + ((size_t)bt * NP + n) * 64 + kq * 8);
        const bf16x8 bq0 = qp[0], bq1 = qp[4];
        const unsigned short* kbase = kws + ((size_t)bt * NP + nl) * 64 + kq * 8;

        f32x4 acc[5] = {};
        #pragma unroll
        for (int i = 0; i < 5; ++i) {
            const int ct = wm * 5 + i;
            const unsigned short* kb = kbase + (size_t)ct * 16 * 64;
            const bf16x8 a0 = *(const bf16x8*)(kb);
            const bf16x8 a1 = *(const bf16x8*)(kb + 32);
            acc[i] = __builtin_amdgcn_mfma_f32_16x16x32_bf16(a0, bq0, acc[i], 0, 0, 0);
            acc[i] = __builtin_amdgcn_mfma_f32_16x16x32_bf16(a1, bq1, acc[i], 0, 0, 0);
        }

        // mask + scale, per-lane max over this wave's 20 m-values
        float mx = -INFINITY;
        #pragma unroll
        for (int i = 0; i < 5; ++i) {
            const int ct = wm * 5 + i;
            const int m0 = ct * 16 + kq * 4;
            float sv[4];
            sv[0] = mv[i][0] ? acc[i][0] * SCALE : -1e9f;
            sv[1] = mv[i][1] ? acc[i][1] * SCALE : -1e9f;
            sv[2] = mv[i][2] ? acc[i][2] * SCALE : -1e9f;
            sv[3] = mv[i][3] ? acc[i][3] * SCALE : -1e9f;
            if (ct == 19) {                  // pad columns m >= 307 (wave-uniform)
                #pragma unroll
                for (int r = 0; r < 4; ++r)
                    if (m0 + r >= PN) sv[r] = -INFINITY;
            }
            #pragma unroll
            for (int r = 0; r < 4; ++r) { acc[i][r] = sv[r]; mx = fmaxf(mx, sv[r]); }
        }
        mx = fmaxf(mx, __shfl_xor(mx, 16));
        mx = fmaxf(mx, __shfl_xor(mx, 32));
        if (lane < 16) redmx[p][wm][lane] = mx;
        __syncthreads();
        const float gmx = fmaxf(fmaxf(redmx[p][0][nl], redmx[p][1][nl]),
                                fmaxf(redmx[p][2][nl], redmx[p][3][nl]));

        float sum = 0.f;
        #pragma unroll
        for (int i = 0; i < 5; ++i) {
            #pragma unroll
            for (int r = 0; r < 4; ++r) {
                const float pw = __expf(acc[i][r] - gmx);
                acc[i][r] = pw;
                sum += pw;
            }
        }
        sum += __shfl_xor(sum, 16);
        sum += __shfl_xor(sum, 32);
        if (lane < 16) redsm[p][wm][lane] = sum;
        __syncthreads();
        const float inv = 1.0f / (redsm[p][0][nl] + redsm[p][1][nl] +
                                  redsm[p][2][nl] + redsm[p][3][nl]);

        if (n < PN) {
            float* orow = out + ((size_t)bt * PN + n) * PN;
            #pragma unroll
            for (int i = 0; i < 5; ++i) {
                const int ct = wm * 5 + i;
                const int m0 = ct * 16 + kq * 4;
                if (ct < 19) {
                    f32x4u o;
                    o[0] = acc[i][0] * inv; o[1] = acc[i][1] * inv;
                    o[2] = acc[i][2] * inv; o[3] = acc[i][3] * inv;
                    *(f32x4u*)(orow + m0) = o;
                } else {
                    #pragma unroll
                    for (int r = 0; r < 4; ++r)
                        if (m0 + r < PN) orow[m0 + r] = acc[i][r] * inv;
                }
            }
        }
        // no trailing barrier: next tt writes the other parity buffer, and
        // the two barriers above bound how far any wave can run ahead.
    }
}

extern "C" void kernel_launch(void* const* d_in, const int* in_sizes, int n_in,
                              void* d_out, int out_size, void* d_ws, size_t ws_size,
                              hipStream_t stream) {
    const float* x  = (const float*)d_in[0];
    const int* mask = (const int*)d_in[1];
    const float* Wq = (const float*)d_in[2];
    const float* bq = (const float*)d_in[3];
    const float* Wk = (const float*)d_in[4];
    const float* bk = (const float*)d_in[5];
    float* out = (float*)d_out;

    // workspace: qws bf16 [96][320][64], kws bf16 [96][320][64]  (7.86 MB)
    unsigned short* qws = (unsigned short*)d_ws;
    unsigned short* kws = qws + (size_t)96 * NP * 64;

    qk_proj_kernel<<<dim3(96 * 10), dim3(256), 0, stream>>>(x, Wq, bq, Wk, bk, qws, kws);
    attn_kernel<<<dim3(8 * 3 * 20), dim3(256), 0, stream>>>(qws, kws, mask, out);
}

// Round 11
// 104.153 us; speedup vs baseline: 1.4340x; 1.0001x over previous
//
#include <hip/hip_runtime.h>
#include <math.h>

// Problem constants
#define PB 8
#define PT 12
#define PN 307
#define NP 320                      // padded N for MFMA tiling
#define SCALE 0.35355339059327373f  // 1/sqrt(8)

typedef short bf16x8 __attribute__((ext_vector_type(8)));
typedef float f32x4  __attribute__((ext_vector_type(4)));
// 4-byte-aligned vectors for rows whose base is only 4B-aligned (307-stride)
typedef int   i32x4u __attribute__((ext_vector_type(4), aligned(4)));
typedef float f32x4u __attribute__((ext_vector_type(4), aligned(4)));

__device__ __forceinline__ unsigned short f32_to_bf16(float v) {
    unsigned u = __float_as_uint(v);
    u += 0x7FFFu + ((u >> 16) & 1u);   // RNE
    return (unsigned short)(u >> 16);
}

__device__ __forceinline__ bf16x8 pack8(float4 lo, float4 hi) {
    bf16x8 r;
    r[0] = (short)f32_to_bf16(lo.x); r[1] = (short)f32_to_bf16(lo.y);
    r[2] = (short)f32_to_bf16(lo.z); r[3] = (short)f32_to_bf16(lo.w);
    r[4] = (short)f32_to_bf16(hi.x); r[5] = (short)f32_to_bf16(hi.y);
    r[6] = (short)f32_to_bf16(hi.z); r[7] = (short)f32_to_bf16(hi.w);
    return r;
}

// ---------------------------------------------------------------------------
// Kernel A — EXACT R6/R9 version (measured-good; do not touch).
// ---------------------------------------------------------------------------
__global__ __launch_bounds__(256) void qk_proj_kernel(
    const float* __restrict__ x,
    const float* __restrict__ Wq, const float* __restrict__ bq,
    const float* __restrict__ Wk, const float* __restrict__ bk,
    unsigned short* __restrict__ qws, unsigned short* __restrict__ kws)
{
    const int tid  = threadIdx.x;
    const int lane = tid & 63;
    const int wv   = tid >> 6;
    const int wn   = wv & 1;
    const int we   = wv >> 1;
    const int chunk = blockIdx.x % 10;
    const int bt    = blockIdx.x / 10;
    const int b = bt / PT, t = bt % PT;
    const int rlo = lane & 15;
    const int kq  = lane >> 4;
    const int n0  = chunk * 32 + wn * 16;        // wave's n-tile base

    const int nn = min(n0 + rlo, PN - 1);
    const float* xrow = x + ((size_t)b * 64 * PT + t) * PN + nn;  // + c*PT*PN
    bf16x8 a[2];
    #pragma unroll
    for (int ks = 0; ks < 2; ++ks) {
        #pragma unroll
        for (int j = 0; j < 8; ++j) {
            const int c = ks * 32 + kq * 8 + j;
            a[ks][j] = (short)f32_to_bf16(xrow[(size_t)c * PT * PN]);
        }
    }

    f32x4 accq[2] = {}, acck[2] = {};
    #pragma unroll
    for (int eti = 0; eti < 2; ++eti) {
        const int e_row = we * 32 + eti * 16 + rlo;
        const float* wq_r = Wq + (size_t)e_row * 64 + kq * 8;
        const float* wk_r = Wk + (size_t)e_row * 64 + kq * 8;
        #pragma unroll
        for (int ks = 0; ks < 2; ++ks) {
            const bf16x8 bqf = pack8(*(const float4*)(wq_r + ks * 32),
                                     *(const float4*)(wq_r + ks * 32 + 4));
            const bf16x8 bkf = pack8(*(const float4*)(wk_r + ks * 32),
                                     *(const float4*)(wk_r + ks * 32 + 4));
            accq[eti] = __builtin_amdgcn_mfma_f32_16x16x32_bf16(a[ks], bqf, accq[eti], 0, 0, 0);
            acck[eti] = __builtin_amdgcn_mfma_f32_16x16x32_bf16(a[ks], bkf, acck[eti], 0, 0, 0);
        }
    }

    #pragma unroll
    for (int eti = 0; eti < 2; ++eti) {
        const int e = we * 32 + eti * 16 + rlo;
        const float bqv = bq[e], bkv = bk[e];
        #pragma unroll
        for (int r = 0; r < 4; ++r) {
            const int n = n0 + kq * 4 + r;
            if (n < PN) {
                qws[((size_t)bt * NP + n) * 64 + e] = f32_to_bf16(accq[eti][r] + bqv);
                kws[((size_t)bt * NP + n) * 64 + e] = f32_to_bf16(acck[eti][r] + bkv);
            }
        }
    }
}

// ---------------------------------------------------------------------------
// Kernel B v7 = R9 structure + (1) one-barrier online softmax per tt
// (wave publishes (mx, sum_local); global combine gsum = sum_w * exp(mx_w -
// gmx); store-time factor = exp(mx-gmx)/gsum) and (2) software pipelining:
// tt loop fully unrolled, tt+1's Q/K fragment loads issued before tt's
// barrier so their ~500-cyc latency hides behind exp + barrier + stores.
// Grid 480: bid = (b*3 + tg)*20 + ntile (R9's proven locality ordering).
// ---------------------------------------------------------------------------
__global__ __launch_bounds__(256) void attn_kernel(
    const unsigned short* __restrict__ qws,
    const unsigned short* __restrict__ kws,
    const int* __restrict__ mask,
    float* __restrict__ out)
{
    __shared__ float2 red[2][4][16];         // (mx, sum), parity-buffered

    const int tid  = threadIdx.x;
    const int lane = tid & 63;
    const int wm   = tid >> 6;               // m-quarter
    const int bid   = blockIdx.x;
    const int ntile = bid % 20;
    const int r2    = bid / 20;
    const int tg    = r2 % 3;
    const int b     = r2 / 3;
    const int ng  = ntile * 16;
    const int nl  = lane & 15;
    const int kq  = lane >> 4;
    const int n   = ng + nl;
    const int nn  = (n < PN) ? n : (PN - 1); // clamp for mask row reads

    // ---- mask fragments: loaded once, reused for all 4 t iterations
    const int* mrow = mask + ((size_t)b * PN + nn) * PN;
    i32x4u mv[5];
    #pragma unroll
    for (int i = 0; i < 5; ++i)
        mv[i] = *(const i32x4u*)(mrow + (wm * 5 + i) * 16 + kq * 4);

    const int bt0 = b * PT + tg * 4;
    // fragment base addresses (advance by NP*64 per t)
    const unsigned short* qb0 = qws + ((size_t)bt0 * NP + n) * 64 + kq * 8;
    const unsigned short* kb0 = kws + ((size_t)bt0 * NP + nl) * 64 + kq * 8;

    // ---- preload tt=0 fragments
    bf16x8 bq0 = *(const bf16x8*)(qb0);
    bf16x8 bq1 = *(const bf16x8*)(qb0 + 32);
    bf16x8 ka[5], kb[5];
    #pragma unroll
    for (int i = 0; i < 5; ++i) {
        const unsigned short* kp = kb0 + (size_t)(wm * 5 + i) * 16 * 64;
        ka[i] = *(const bf16x8*)(kp);
        kb[i] = *(const bf16x8*)(kp + 32);
    }

    #pragma unroll
    for (int tt = 0; tt < 4; ++tt) {
        const int bt = bt0 + tt;
        const int p  = tt & 1;

        f32x4 acc[5] = {};
        #pragma unroll
        for (int i = 0; i < 5; ++i) {
            acc[i] = __builtin_amdgcn_mfma_f32_16x16x32_bf16(ka[i], bq0, acc[i], 0, 0, 0);
            acc[i] = __builtin_amdgcn_mfma_f32_16x16x32_bf16(kb[i], bq1, acc[i], 0, 0, 0);
        }

        // ---- prefetch tt+1 fragments (issued before the barrier; latency
        // hides behind exp/barrier/store phase below)
        if (tt < 3) {
            const size_t off = (size_t)(tt + 1) * NP * 64;
            bq0 = *(const bf16x8*)(qb0 + off);
            bq1 = *(const bf16x8*)(qb0 + off + 32);
            #pragma unroll
            for (int i = 0; i < 5; ++i) {
                const unsigned short* kp = kb0 + off + (size_t)(wm * 5 + i) * 16 * 64;
                ka[i] = *(const bf16x8*)(kp);
                kb[i] = *(const bf16x8*)(kp + 32);
            }
        }

        // ---- mask + scale, wave-local max over 20 m-values
        float mx = -INFINITY;
        #pragma unroll
        for (int i = 0; i < 5; ++i) {
            const int ct = wm * 5 + i;
            const int m0 = ct * 16 + kq * 4;
            float sv[4];
            sv[0] = mv[i][0] ? acc[i][0] * SCALE : -1e9f;
            sv[1] = mv[i][1] ? acc[i][1] * SCALE : -1e9f;
            sv[2] = mv[i][2] ? acc[i][2] * SCALE : -1e9f;
            sv[3] = mv[i][3] ? acc[i][3] * SCALE : -1e9f;
            if (ct == 19) {                  // pad columns m >= 307 (wave-uniform)
                #pragma unroll
                for (int r = 0; r < 4; ++r)
                    if (m0 + r >= PN) sv[r] = -INFINITY;
            }
            #pragma unroll
            for (int r = 0; r < 4; ++r) { acc[i][r] = sv[r]; mx = fmaxf(mx, sv[r]); }
        }
        mx = fmaxf(mx, __shfl_xor(mx, 16));
        mx = fmaxf(mx, __shfl_xor(mx, 32));   // mx >= -1e9 always (307 valid m)

        // ---- wave-local sum of exp(s - mx)
        float sum = 0.f;
        #pragma unroll
        for (int i = 0; i < 5; ++i) {
            #pragma unroll
            for (int r = 0; r < 4; ++r) {
                const float pw = __expf(acc[i][r] - mx);
                acc[i][r] = pw;
                sum += pw;
            }
        }
        sum += __shfl_xor(sum, 16);
        sum += __shfl_xor(sum, 32);

        if (lane < 16) red[p][wm][lane] = make_float2(mx, sum);
        __syncthreads();                      // the ONLY barrier this tt

        const float2 r0 = red[p][0][nl], r1 = red[p][1][nl];
        const float2 r2v = red[p][2][nl], r3 = red[p][3][nl];
        const float gmx = fmaxf(fmaxf(r0.x, r1.x), fmaxf(r2v.x, r3.x));
        const float gsum = r0.y * __expf(r0.x - gmx) + r1.y * __expf(r1.x - gmx)
                         + r2v.y * __expf(r2v.x - gmx) + r3.y * __expf(r3.x - gmx);
        const float factor = __expf(mx - gmx) / gsum;

        if (n < PN) {
            float* orow = out + ((size_t)bt * PN + n) * PN;
            #pragma unroll
            for (int i = 0; i < 5; ++i) {
                const int ct = wm * 5 + i;
                const int m0 = ct * 16 + kq * 4;
                if (ct < 19) {
                    f32x4u o;
                    o[0] = acc[i][0] * factor; o[1] = acc[i][1] * factor;
                    o[2] = acc[i][2] * factor; o[3] = acc[i][3] * factor;
                    *(f32x4u*)(orow + m0) = o;
                } else {
                    #pragma unroll
                    for (int r = 0; r < 4; ++r)
                        if (m0 + r < PN) orow[m0 + r] = acc[i][r] * factor;
                }
            }
        }
        // no trailing barrier: parity buffer + next tt's barrier bound skew.
    }
}

extern "C" void kernel_launch(void* const* d_in, const int* in_sizes, int n_in,
                              void* d_out, int out_size, void* d_ws, size_t ws_size,
                              hipStream_t stream) {
    const float* x  = (const float*)d_in[0];
    const int* mask = (const int*)d_in[1];
    const float* Wq = (const float*)d_in[2];
    const float* bq = (const float*)d_in[3];
    const float* Wk = (const float*)d_in[4];
    const float* bk = (const float*)d_in[5];
    float* out = (float*)d_out;

    // workspace: qws bf16 [96][320][64], kws bf16 [96][320][64]  (7.86 MB)
    unsigned short* qws = (unsigned short*)d_ws;
    unsigned short* kws = qws + (size_t)96 * NP * 64;

    qk_proj_kernel<<<dim3(96 * 10), dim3(256), 0, stream>>>(x, Wq, bq, Wk, bk, qws, kws);
    attn_kernel<<<dim3(8 * 3 * 20), dim3(256), 0, stream>>>(qws, kws, mask, out);
}